// Round 1
// baseline (17.067 us; speedup 1.0000x reference)
//
#include <hip/hip_runtime.h>

// GCN_10934986735728
//
// Key identity: the reference applies training-mode BatchNorm (normalizing
// over the node axis with the batch's own mean) and then IMMEDIATELY takes
// the global mean over that same node axis. For any per-channel affine BN,
//     mean_nodes(bn(h)) = (mean(h) - mean(h)) * rsqrt(var+eps) * gamma + beta
//                       = beta  (= be3)
// so the pooled feature vector equals be3 exactly, independent of x,
// edge_index, and every conv/BN parameter before it. The output reduces to
//     log_softmax(((be3 @ lw1 + lb1) @ lw2 + lb2) @ lw3 + lb3)
// which is a tiny 3-layer MLP on a single [512] vector.

#define H1 128   // lw1 out dim (2H)
#define H2 64    // lw2 out dim (H)
#define NC 10    // classes
#define D3 512   // 8H

__global__ __launch_bounds__(128) void gcn_collapsed_head(
    const float* __restrict__ be3,   // [512]
    const float* __restrict__ lw1,   // [512,128] row-major
    const float* __restrict__ lb1,   // [128]
    const float* __restrict__ lw2,   // [128,64]
    const float* __restrict__ lb2,   // [64]
    const float* __restrict__ lw3,   // [64,10]
    const float* __restrict__ lb3,   // [10]
    float* __restrict__ out)         // [10]
{
    __shared__ float t1[H1];
    __shared__ float t2[H2];
    __shared__ float t3[NC];
    const int tid = threadIdx.x;

    // t1 = be3 @ lw1 + lb1   (thread j owns output channel j; reads of
    // lw1[k*128 + j] are coalesced across the 128 threads for each k)
    {
        float acc = lb1[tid];
        #pragma unroll 8
        for (int k = 0; k < D3; ++k)
            acc = fmaf(be3[k], lw1[k * H1 + tid], acc);
        t1[tid] = acc;
    }
    __syncthreads();

    // t2 = t1 @ lw2 + lb2
    if (tid < H2) {
        float acc = lb2[tid];
        #pragma unroll 8
        for (int k = 0; k < H1; ++k)
            acc = fmaf(t1[k], lw2[k * H2 + tid], acc);
        t2[tid] = acc;
    }
    __syncthreads();

    // t3 = t2 @ lw3 + lb3
    if (tid < NC) {
        float acc = lb3[tid];
        #pragma unroll
        for (int k = 0; k < H2; ++k)
            acc = fmaf(t2[k], lw3[k * NC + tid], acc);
        t3[tid] = acc;
    }
    __syncthreads();

    // log_softmax over the 10 logits (serial in lane 0 — 10 elements)
    if (tid == 0) {
        float m = t3[0];
        for (int i = 1; i < NC; ++i) m = fmaxf(m, t3[i]);
        float s = 0.0f;
        for (int i = 0; i < NC; ++i) s += expf(t3[i] - m);
        const float lse = m + logf(s);
        for (int i = 0; i < NC; ++i) out[i] = t3[i] - lse;
    }
}

extern "C" void kernel_launch(void* const* d_in, const int* in_sizes, int n_in,
                              void* d_out, int out_size, void* d_ws, size_t ws_size,
                              hipStream_t stream) {
    (void)in_sizes; (void)n_in; (void)d_ws; (void)ws_size; (void)out_size;
    const float* be3 = (const float*)d_in[15];
    const float* lw1 = (const float*)d_in[16];
    const float* lb1 = (const float*)d_in[17];
    const float* lw2 = (const float*)d_in[18];
    const float* lb2 = (const float*)d_in[19];
    const float* lw3 = (const float*)d_in[20];
    const float* lb3 = (const float*)d_in[21];
    float* out = (float*)d_out;

    gcn_collapsed_head<<<1, 128, 0, stream>>>(be3, lw1, lb1, lw2, lb2, lw3, lb3, out);
}

// Round 2
// 10.202 us; speedup vs baseline: 1.6728x; 1.6728x over previous
//
#include <hip/hip_runtime.h>

// GCN_10934986735728
//
// Identity: training-mode BatchNorm over the node axis followed by
// global_mean_pool over that same axis yields exactly beta (be3):
//     mean_nodes(bn(h)) = (mean(h)-mean(h))*rsqrt(var+eps)*gamma + beta = be3
// so the whole graph/conv pipeline is dead code and the output is
//     log_softmax(((be3 @ lw1 + lb1) @ lw2 + lb2) @ lw3 + lb3).
//
// This round: split-K within one 1024-thread block to hide L2/HBM latency
// on the 256 KB lw1 read (was a 512-deep serial loop on 2 waves).

#define D3 512   // 8H
#define H1 128   // 2H
#define H2 64    // H
#define NC 10

__global__ __launch_bounds__(1024) void gcn_collapsed_head(
    const float* __restrict__ be3,   // [512]
    const float* __restrict__ lw1,   // [512,128] row-major
    const float* __restrict__ lb1,   // [128]
    const float* __restrict__ lw2,   // [128,64]
    const float* __restrict__ lb2,   // [64]
    const float* __restrict__ lw3,   // [64,10]
    const float* __restrict__ lb3,   // [10]
    float* __restrict__ out)         // [10]
{
    __shared__ float p1[32][H1];     // 16 KB split-K partials, layer 1
    __shared__ float t1[H1];
    __shared__ float p2[16][H2];     // 4 KB split-K partials, layer 2
    __shared__ float t2[H2];
    __shared__ float t3[NC];
    const int tid = threadIdx.x;

    // ---- layer 1: t1 = be3 @ lw1 + lb1 ----------------------------------
    // 32 k-slices x 16 k each; each thread owns 4 consecutive output cols
    // via float4 (16 B/lane coalesced; whole block keeps 1024 loads in flight).
    {
        const int jg = tid & 31;          // column group: cols [4*jg, 4*jg+4)
        const int sl = tid >> 5;          // k-slice 0..31
        const int k0 = sl * 16;
        float4 acc = {0.f, 0.f, 0.f, 0.f};
        const float4* __restrict__ w4 = (const float4*)lw1;  // [512][32]
        #pragma unroll
        for (int kk = 0; kk < 16; ++kk) {
            const int k = k0 + kk;
            const float b = be3[k];
            const float4 w = w4[k * 32 + jg];
            acc.x = fmaf(b, w.x, acc.x);
            acc.y = fmaf(b, w.y, acc.y);
            acc.z = fmaf(b, w.z, acc.z);
            acc.w = fmaf(b, w.w, acc.w);
        }
        ((float4*)&p1[sl][0])[jg] = acc;
    }
    __syncthreads();
    if (tid < H1) {
        float acc = lb1[tid];
        #pragma unroll
        for (int s = 0; s < 32; ++s) acc += p1[s][tid];  // conflict-free cols
        t1[tid] = acc;
    }
    __syncthreads();

    // ---- layer 2: t2 = t1 @ lw2 + lb2 ------------------------------------
    // 16 k-slices x 8 k each, scalar coalesced loads of lw2.
    {
        const int j  = tid & 63;
        const int sl = tid >> 6;          // 0..15
        const int k0 = sl * 8;
        float acc = 0.f;
        #pragma unroll
        for (int kk = 0; kk < 8; ++kk) {
            const int k = k0 + kk;
            acc = fmaf(t1[k], lw2[k * H2 + j], acc);
        }
        p2[sl][j] = acc;
    }
    __syncthreads();
    if (tid < H2) {
        float acc = lb2[tid];
        #pragma unroll
        for (int s = 0; s < 16; ++s) acc += p2[s][tid];
        t2[tid] = acc;
    }
    __syncthreads();

    // ---- layer 3: t3 = t2 @ lw3 + lb3 (640 floats, trivial) --------------
    if (tid < NC) {
        float acc = lb3[tid];
        #pragma unroll
        for (int k = 0; k < H2; ++k)
            acc = fmaf(t2[k], lw3[k * NC + tid], acc);
        t3[tid] = acc;
    }
    __syncthreads();

    // ---- log_softmax over 10 logits --------------------------------------
    if (tid == 0) {
        float m = t3[0];
        #pragma unroll
        for (int i = 1; i < NC; ++i) m = fmaxf(m, t3[i]);
        float s = 0.0f;
        #pragma unroll
        for (int i = 0; i < NC; ++i) s += expf(t3[i] - m);
        const float lse = m + logf(s);
        #pragma unroll
        for (int i = 0; i < NC; ++i) out[i] = t3[i] - lse;
    }
}

extern "C" void kernel_launch(void* const* d_in, const int* in_sizes, int n_in,
                              void* d_out, int out_size, void* d_ws, size_t ws_size,
                              hipStream_t stream) {
    (void)in_sizes; (void)n_in; (void)d_ws; (void)ws_size; (void)out_size;
    const float* be3 = (const float*)d_in[15];
    const float* lw1 = (const float*)d_in[16];
    const float* lb1 = (const float*)d_in[17];
    const float* lw2 = (const float*)d_in[18];
    const float* lb2 = (const float*)d_in[19];
    const float* lw3 = (const float*)d_in[20];
    const float* lb3 = (const float*)d_in[21];
    float* out = (float*)d_out;

    gcn_collapsed_head<<<1, 1024, 0, stream>>>(be3, lw1, lb1, lw2, lb2, lw3, lb3, out);
}

// Round 3
// 9.888 us; speedup vs baseline: 1.7261x; 1.0318x over previous
//
#include <hip/hip_runtime.h>
#include <stdint.h>

// GCN_10934986735728
//
// Identity 1: training-mode BatchNorm over the node axis followed by
// global_mean_pool over that same axis yields exactly beta (be3):
//     mean_nodes(bn(h)) = (mean(h)-mean(h))*rsqrt(var+eps)*gamma + beta = be3
// so the graph/conv pipeline is dead code and the output is
//     log_softmax(((be3 @ lw1 + lb1) @ lw2 + lb2) @ lw3 + lb3).
//
// Identity 2: the MLP head is LINEAR (no activations), so the logits are a
// sum over k-slices of lw1:  z = sum_b ((be3_b @ lw1_b) @ lw2) @ lw3 (+bias
// chain, folded into block 0's slice). This lets 16 blocks (16 CUs) stream
// lw1 in parallel — the single-CU 256 KB stream was the kernel bottleneck —
// each producing a 10-float contribution, combined in block 0 via
// agent-scope release/acquire flags in d_ws (single dispatch; a second
// kernel node would cost more than it saves).

#define D3 512
#define H1 128
#define H2 64
#define NC 10
#define NPROD 16
#define MAGIC 0x9E3779B1u

__global__ __launch_bounds__(256) void gcn_head_mc(
    const float* __restrict__ be3,   // [512]
    const float* __restrict__ lw1,   // [512,128]
    const float* __restrict__ lb1,   // [128]
    const float* __restrict__ lw2,   // [128,64]
    const float* __restrict__ lb2,   // [64]
    const float* __restrict__ lw3,   // [64,10]
    const float* __restrict__ lb3,   // [10]
    float* __restrict__ out,         // [10]
    float* __restrict__ ws)          // scratch: slots [16][16]f + flags
{
    const int b   = blockIdx.x;
    const int tid = threadIdx.x;

    __shared__ float p1[8][H1];
    __shared__ float t1p[H1];
    __shared__ float p2[4][H2];
    __shared__ float c2s[H2];
    __shared__ float zs[16];

    float*    slots = ws;                          // 16 slots x 64 B
    uint32_t* flags = (uint32_t*)(ws + 256);       // 16 flags x 64 B stride

    // ---- layer-1 partial: k in [32b, 32b+32), all 16 blocks in parallel ---
    {
        const int jg = tid & 31;          // float4 column group (128 cols)
        const int kk = tid >> 5;          // 0..7
        const float4* __restrict__ w4 = (const float4*)lw1;  // [512][32]
        float4 acc = {0.f, 0.f, 0.f, 0.f};
        #pragma unroll
        for (int i = 0; i < 4; ++i) {
            const int k = 32 * b + kk + 8 * i;
            const float s = be3[k];
            const float4 w = w4[k * 32 + jg];
            acc.x = fmaf(s, w.x, acc.x);
            acc.y = fmaf(s, w.y, acc.y);
            acc.z = fmaf(s, w.z, acc.z);
            acc.w = fmaf(s, w.w, acc.w);
        }
        ((float4*)&p1[kk][0])[jg] = acc;
    }
    __syncthreads();
    if (tid < H1) {
        float a = (b == 0) ? lb1[tid] : 0.f;   // fold bias chain into block 0
        #pragma unroll
        for (int s = 0; s < 8; ++s) a += p1[s][tid];
        t1p[tid] = a;
    }
    __syncthreads();

    // ---- layer-2: c2 = t1p @ lw2 (+lb2 on block 0) ------------------------
    {
        const int j  = tid & 63;
        const int sl = tid >> 6;          // 0..3
        float a = 0.f;
        #pragma unroll
        for (int kk = 0; kk < 32; ++kk) {
            const int k = sl * 32 + kk;
            a = fmaf(t1p[k], lw2[k * H2 + j], a);
        }
        p2[sl][j] = a;
    }
    __syncthreads();
    if (tid < H2) {
        float a = (b == 0) ? lb2[tid] : 0.f;
        a += p2[0][tid] + p2[1][tid] + p2[2][tid] + p2[3][tid];
        c2s[tid] = a;
    }
    __syncthreads();

    // ---- layer-3: 10-float contribution, publish to ws --------------------
    if (tid < NC) {
        float a = (b == 0) ? lb3[tid] : 0.f;
        #pragma unroll
        for (int k = 0; k < H2; ++k)
            a = fmaf(c2s[k], lw3[k * NC + tid], a);
        __hip_atomic_store(&slots[b * 16 + tid], a,
                           __ATOMIC_RELAXED, __HIP_MEMORY_SCOPE_AGENT);
    }
    __threadfence();
    __syncthreads();
    if (tid == 0)
        __hip_atomic_store(&flags[b * 16], MAGIC,
                           __ATOMIC_RELEASE, __HIP_MEMORY_SCOPE_AGENT);

    if (b != 0) return;

    // ---- consumer (block 0): combine 16 contributions + log_softmax -------
    if (tid < NPROD) {
        while (__hip_atomic_load(&flags[tid * 16],
                                 __ATOMIC_ACQUIRE, __HIP_MEMORY_SCOPE_AGENT)
               != MAGIC) { /* spin; 16 blocks are co-resident on 256 CUs */ }
    }
    __syncthreads();
    if (tid < NC) {
        float z = 0.f;
        #pragma unroll
        for (int bb = 0; bb < NPROD; ++bb)     // fixed order: deterministic
            z += __hip_atomic_load(&slots[bb * 16 + tid],
                                   __ATOMIC_RELAXED, __HIP_MEMORY_SCOPE_AGENT);
        zs[tid] = z;
    }
    __syncthreads();
    if (tid < NPROD)   // re-arm flags so every call waits honestly
        __hip_atomic_store(&flags[tid * 16], 0u,
                           __ATOMIC_RELAXED, __HIP_MEMORY_SCOPE_AGENT);
    if (tid == 0) {
        float m = zs[0];
        #pragma unroll
        for (int i = 1; i < NC; ++i) m = fmaxf(m, zs[i]);
        float s = 0.f;
        #pragma unroll
        for (int i = 0; i < NC; ++i) s += expf(zs[i] - m);
        const float lse = m + logf(s);
        #pragma unroll
        for (int i = 0; i < NC; ++i) out[i] = zs[i] - lse;
    }
}

extern "C" void kernel_launch(void* const* d_in, const int* in_sizes, int n_in,
                              void* d_out, int out_size, void* d_ws, size_t ws_size,
                              hipStream_t stream) {
    (void)in_sizes; (void)n_in; (void)ws_size; (void)out_size;
    const float* be3 = (const float*)d_in[15];
    const float* lw1 = (const float*)d_in[16];
    const float* lb1 = (const float*)d_in[17];
    const float* lw2 = (const float*)d_in[18];
    const float* lb2 = (const float*)d_in[19];
    const float* lw3 = (const float*)d_in[20];
    const float* lb3 = (const float*)d_in[21];
    float* out = (float*)d_out;
    float* ws  = (float*)d_ws;

    gcn_head_mc<<<NPROD, 256, 0, stream>>>(be3, lw1, lb1, lw2, lb2, lw3, lb3,
                                           out, ws);
}